// Round 1
// baseline (573.906 us; speedup 1.0000x reference)
//
#include <hip/hip_runtime.h>
#include <cstdint>
#include <cstddef>

// ---------------------------------------------------------------------------
// EnhancedObj: visual/object attention block, bf16-MFMA implementation.
// Shapes (hardcoded from reference): bs=8, F=64, obj=36, d=2048.
//   MO = 8*64*36 = 18432 object rows, MV = 8*64 = 512 visual rows, NOBJ=2304.
// Pipeline:
//   wprep:  W[k][n] fp32 -> Wt[n][k] bf16 (transpose+convert)   x2
//   gemm_xw: Y = X @ W + b   (fp32 A converted in-stage, bf16 MFMA, fp32 out)
//   ep_ln:  t=tanh(Y[+Y2]); LN(t)*g+b -> bf16 and/or fp32
//   troe:   oe[n][d] -> oeT[d][n]  (bf16 tile transpose)
//   gemm_adj: adjT[b][f][n] = (oe . ve)/sqrt(d)   (write transposed)
//   smax:   softmax over n (rows of adjT), out bf16
//   gemm_agg: agg[b][f][d] = adj_sm @ oeT
//   ep_ln:  out = LN(tanh(agg + ve))
// ---------------------------------------------------------------------------

typedef __attribute__((ext_vector_type(4))) float f32x4;
typedef __attribute__((ext_vector_type(4))) unsigned int u32x4;
typedef __attribute__((ext_vector_type(8))) short bf16x8;

#define DD 2048
#define BS 8
#define FF 64
#define NOBJ 2304
#define MO 18432
#define MV 512

__device__ __forceinline__ unsigned short f2bf(float f) {
  unsigned int u = __float_as_uint(f);
  u += 0x7fffu + ((u >> 16) & 1u);          // RTNE (inputs finite, no NaN path)
  return (unsigned short)(u >> 16);
}
__device__ __forceinline__ unsigned int pk2(float a, float b) {
  return (unsigned int)f2bf(a) | ((unsigned int)f2bf(b) << 16);
}

// --------------------------------------------------------------------------
// W[k][n] fp32 (2048x2048) -> Wt[n][k] bf16. 64x64 tiles via LDS.
// --------------------------------------------------------------------------
__global__ __launch_bounds__(256) void k_wprep(const float* __restrict__ W,
                                               unsigned short* __restrict__ Wt) {
  __shared__ unsigned short sh[64][65];
  const int t = threadIdx.x;
  const int kb = blockIdx.x * 64, nb = blockIdx.y * 64;
  {
    const int rk = t >> 2, seg = t & 3;
    const float* src = W + (size_t)(kb + rk) * DD + nb + seg * 16;
#pragma unroll
    for (int q = 0; q < 4; ++q) {
      f32x4 x = *(const f32x4*)(src + q * 4);
      sh[rk][seg * 16 + q * 4 + 0] = f2bf(x.x);
      sh[rk][seg * 16 + q * 4 + 1] = f2bf(x.y);
      sh[rk][seg * 16 + q * 4 + 2] = f2bf(x.z);
      sh[rk][seg * 16 + q * 4 + 3] = f2bf(x.w);
    }
  }
  __syncthreads();
  {
    const int nn = t >> 2, ks = t & 3;
    unsigned int o[8];
#pragma unroll
    for (int j = 0; j < 8; ++j)
      o[j] = (unsigned int)sh[ks * 16 + 2 * j][nn] |
             ((unsigned int)sh[ks * 16 + 2 * j + 1][nn] << 16);
    u32x4 p0 = {o[0], o[1], o[2], o[3]};
    u32x4 p1 = {o[4], o[5], o[6], o[7]};
    unsigned short* dst = Wt + (size_t)(nb + nn) * DD + kb + ks * 16;
    ((u32x4*)dst)[0] = p0;
    ((u32x4*)dst)[1] = p1;
  }
}

// --------------------------------------------------------------------------
// Y[M][2048] = X[M][2048](fp32) @ W + bias, via bf16 MFMA.
// Wt is pre-transposed bf16 [n][k]. BM=BN=128, BK=32, 256 thr (4 waves 2x2).
// grid = (16, M/128)
// --------------------------------------------------------------------------
__global__ __launch_bounds__(256) void k_gemm_xw(const float* __restrict__ X,
                                                 const unsigned short* __restrict__ Wt,
                                                 const float* __restrict__ bias,
                                                 float* __restrict__ Y) {
  __shared__ __align__(16) unsigned short As[128 * 32];
  __shared__ __align__(16) unsigned short Bs[128 * 32];
  const int t = threadIdx.x;
  const int lane = t & 63, wave = t >> 6;
  const int r = lane & 15, g = lane >> 4;
  const int wm = wave >> 1, wn = wave & 1;
  const int bm = blockIdx.y * 128, bn = blockIdx.x * 128;
  const int arow = t >> 1, ah = t & 1;   // 2 threads/row, 16 k each
  f32x4 acc[4][4] = {};
  const float* aptr = X + (size_t)(bm + arow) * DD + ah * 16;
  const unsigned short* bptr = Wt + (size_t)(bn + arow) * DD + ah * 16;
  for (int kt = 0; kt < DD / 32; ++kt) {
    const int kb = kt * 32;
    f32x4 a0 = *(const f32x4*)(aptr + kb);
    f32x4 a1 = *(const f32x4*)(aptr + kb + 4);
    f32x4 a2 = *(const f32x4*)(aptr + kb + 8);
    f32x4 a3 = *(const f32x4*)(aptr + kb + 12);
    u32x4 b0 = *(const u32x4*)(bptr + kb);
    u32x4 b1 = *(const u32x4*)(bptr + kb + 8);
    __syncthreads();  // previous iteration's frag reads complete
    u32x4 p0 = {pk2(a0.x, a0.y), pk2(a0.z, a0.w), pk2(a1.x, a1.y), pk2(a1.z, a1.w)};
    u32x4 p1 = {pk2(a2.x, a2.y), pk2(a2.z, a2.w), pk2(a3.x, a3.y), pk2(a3.z, a3.w)};
    ((u32x4*)As)[arow * 4 + ah * 2 + 0] = p0;
    ((u32x4*)As)[arow * 4 + ah * 2 + 1] = p1;
    ((u32x4*)Bs)[arow * 4 + ah * 2 + 0] = b0;
    ((u32x4*)Bs)[arow * 4 + ah * 2 + 1] = b1;
    __syncthreads();
    bf16x8 af[4], bfr[4];
#pragma unroll
    for (int m = 0; m < 4; ++m) af[m] = ((const bf16x8*)As)[(wm * 64 + m * 16 + r) * 4 + g];
#pragma unroll
    for (int n = 0; n < 4; ++n) bfr[n] = ((const bf16x8*)Bs)[(wn * 64 + n * 16 + r) * 4 + g];
#pragma unroll
    for (int m = 0; m < 4; ++m)
#pragma unroll
      for (int n = 0; n < 4; ++n)
        acc[m][n] = __builtin_amdgcn_mfma_f32_16x16x32_bf16(af[m], bfr[n], acc[m][n], 0, 0, 0);
  }
#pragma unroll
  for (int m = 0; m < 4; ++m) {
    const int row0 = bm + wm * 64 + m * 16 + g * 4;
#pragma unroll
    for (int n = 0; n < 4; ++n) {
      const int col = bn + wn * 64 + n * 16 + r;
      const float bv = bias[col];
#pragma unroll
      for (int i = 0; i < 4; ++i)
        Y[(size_t)(row0 + i) * DD + col] = acc[m][n][i] + bv;
    }
  }
}

// --------------------------------------------------------------------------
// Row-wise: t = tanh(Y[row] (+ Y2[row])); LN(t)*g+b -> optional bf16 / fp32.
// One block (256 thr) per row of 2048.
// --------------------------------------------------------------------------
__global__ __launch_bounds__(256) void k_ep_ln(const float* __restrict__ Y,
                                               const float* __restrict__ Y2,
                                               const float* __restrict__ gw,
                                               const float* __restrict__ bw,
                                               unsigned short* __restrict__ obf,
                                               float* __restrict__ of32) {
  const int row = blockIdx.x, t = threadIdx.x;
  const size_t base = (size_t)row * DD + t * 8;
  f32x4 v0 = ((const f32x4*)(Y + base))[0];
  f32x4 v1 = ((const f32x4*)(Y + base))[1];
  if (Y2 != nullptr) {
    v0 += ((const f32x4*)(Y2 + base))[0];
    v1 += ((const f32x4*)(Y2 + base))[1];
  }
  float tv[8];
#pragma unroll
  for (int j = 0; j < 4; ++j) {
    tv[j] = tanhf(v0[j]);
    tv[4 + j] = tanhf(v1[j]);
  }
  float s1 = 0.f, s2 = 0.f;
#pragma unroll
  for (int j = 0; j < 8; ++j) {
    s1 += tv[j];
    s2 += tv[j] * tv[j];
  }
#pragma unroll
  for (int m = 1; m < 64; m <<= 1) {
    s1 += __shfl_xor(s1, m, 64);
    s2 += __shfl_xor(s2, m, 64);
  }
  __shared__ float r1[4], r2[4];
  const int wave = t >> 6;
  if ((t & 63) == 0) {
    r1[wave] = s1;
    r2[wave] = s2;
  }
  __syncthreads();
  const float S1 = r1[0] + r1[1] + r1[2] + r1[3];
  const float S2 = r2[0] + r2[1] + r2[2] + r2[3];
  const float mean = S1 * (1.0f / DD);
  const float var = S2 * (1.0f / DD) - mean * mean;
  const float rstd = rsqrtf(var + 1e-5f);
  f32x4 g0 = ((const f32x4*)(gw + t * 8))[0], g1 = ((const f32x4*)(gw + t * 8))[1];
  f32x4 bb0 = ((const f32x4*)(bw + t * 8))[0], bb1 = ((const f32x4*)(bw + t * 8))[1];
  float o[8];
#pragma unroll
  for (int j = 0; j < 4; ++j) {
    o[j] = (tv[j] - mean) * rstd * g0[j] + bb0[j];
    o[4 + j] = (tv[4 + j] - mean) * rstd * g1[j] + bb1[j];
  }
  if (obf != nullptr) {
    u32x4 p = {pk2(o[0], o[1]), pk2(o[2], o[3]), pk2(o[4], o[5]), pk2(o[6], o[7])};
    *((u32x4*)(obf + base)) = p;
  }
  if (of32 != nullptr) {
    f32x4 w0 = {o[0], o[1], o[2], o[3]}, w1 = {o[4], o[5], o[6], o[7]};
    ((f32x4*)(of32 + base))[0] = w0;
    ((f32x4*)(of32 + base))[1] = w1;
  }
}

// --------------------------------------------------------------------------
// oe[b][n][d] bf16 -> oeT[b][d][n] bf16, 64x64 tiles. grid (36, 32, 8).
// --------------------------------------------------------------------------
__global__ __launch_bounds__(256) void k_troe(const unsigned short* __restrict__ oe,
                                              unsigned short* __restrict__ oeT) {
  __shared__ unsigned short sh[64][65];
  const int t = threadIdx.x;
  const int b = blockIdx.z, nt = blockIdx.x, dt = blockIdx.y;
  {
    const int nn = t >> 2, seg = t & 3;
    const unsigned short* src = oe + ((size_t)b * NOBJ + nt * 64 + nn) * DD + dt * 64 + seg * 16;
    u32x4 x0 = ((const u32x4*)src)[0];
    u32x4 x1 = ((const u32x4*)src)[1];
    const unsigned short* px0 = (const unsigned short*)&x0;
    const unsigned short* px1 = (const unsigned short*)&x1;
#pragma unroll
    for (int j = 0; j < 8; ++j) {
      sh[nn][seg * 16 + j] = px0[j];
      sh[nn][seg * 16 + 8 + j] = px1[j];
    }
  }
  __syncthreads();
  {
    const int dd = t >> 2, ns = t & 3;
    unsigned int o[8];
#pragma unroll
    for (int j = 0; j < 8; ++j)
      o[j] = (unsigned int)sh[ns * 16 + 2 * j][dd] |
             ((unsigned int)sh[ns * 16 + 2 * j + 1][dd] << 16);
    u32x4 p0 = {o[0], o[1], o[2], o[3]};
    u32x4 p1 = {o[4], o[5], o[6], o[7]};
    unsigned short* dst = oeT + ((size_t)b * DD + dt * 64 + dd) * NOBJ + nt * 64 + ns * 16;
    ((u32x4*)dst)[0] = p0;
    ((u32x4*)dst)[1] = p1;
  }
}

// --------------------------------------------------------------------------
// adjT[b][f][n] = (oe[b][n][:] . ve[b][f][:]) / sqrt(2048).
// BM=128(n), BN=64(f), BK=32. grid (18, 8). Waves 2x2, wave tile 64x32.
// --------------------------------------------------------------------------
__global__ __launch_bounds__(256) void k_gemm_adj(const unsigned short* __restrict__ oe,
                                                  const unsigned short* __restrict__ veb,
                                                  float* __restrict__ adjT) {
  __shared__ __align__(16) unsigned short As[128 * 32];
  __shared__ __align__(16) unsigned short Bs[64 * 32];
  const int t = threadIdx.x;
  const int lane = t & 63, wave = t >> 6;
  const int r = lane & 15, g = lane >> 4;
  const int wm = wave >> 1, wn = wave & 1;
  const int b = blockIdx.y, bm = blockIdx.x * 128;
  const int arow = t >> 1, ah = t & 1;
  const int br_ = t >> 2, bseg = t & 3;
  f32x4 acc[4][2] = {};
  const unsigned short* aptr = oe + ((size_t)b * NOBJ + bm + arow) * DD + ah * 16;
  const unsigned short* bptr = veb + ((size_t)b * FF + br_) * DD + bseg * 8;
  for (int kt = 0; kt < DD / 32; ++kt) {
    const int kb = kt * 32;
    u32x4 a0 = ((const u32x4*)(aptr + kb))[0];
    u32x4 a1 = ((const u32x4*)(aptr + kb))[1];
    u32x4 bv = *(const u32x4*)(bptr + kb);
    __syncthreads();
    ((u32x4*)As)[arow * 4 + ah * 2 + 0] = a0;
    ((u32x4*)As)[arow * 4 + ah * 2 + 1] = a1;
    ((u32x4*)Bs)[br_ * 4 + bseg] = bv;
    __syncthreads();
    bf16x8 af[4], bfr[2];
#pragma unroll
    for (int m = 0; m < 4; ++m) af[m] = ((const bf16x8*)As)[(wm * 64 + m * 16 + r) * 4 + g];
#pragma unroll
    for (int n = 0; n < 2; ++n) bfr[n] = ((const bf16x8*)Bs)[(wn * 32 + n * 16 + r) * 4 + g];
#pragma unroll
    for (int m = 0; m < 4; ++m)
#pragma unroll
      for (int n = 0; n < 2; ++n)
        acc[m][n] = __builtin_amdgcn_mfma_f32_16x16x32_bf16(af[m], bfr[n], acc[m][n], 0, 0, 0);
  }
  const float scale = 0.02209708691207961f;  // 1/sqrt(2048)
#pragma unroll
  for (int m = 0; m < 4; ++m)
#pragma unroll
    for (int n = 0; n < 2; ++n) {
      const int f = wn * 32 + n * 16 + r;
      const int n0 = bm + wm * 64 + m * 16 + g * 4;
      f32x4 v = acc[m][n];
      v *= scale;
      *(f32x4*)(adjT + ((size_t)b * FF + f) * NOBJ + n0) = v;
    }
}

// --------------------------------------------------------------------------
// Row softmax over 2304 (rows of adjT), write bf16. grid = 512 rows.
// --------------------------------------------------------------------------
__global__ __launch_bounds__(256) void k_smax(const float* __restrict__ adjT,
                                              unsigned short* __restrict__ out) {
  const int t = threadIdx.x;
  const size_t base = (size_t)blockIdx.x * NOBJ;
  float v[9];
#pragma unroll
  for (int j = 0; j < 9; ++j) v[j] = adjT[base + t + j * 256];
  float m = v[0];
#pragma unroll
  for (int j = 1; j < 9; ++j) m = fmaxf(m, v[j]);
#pragma unroll
  for (int s = 1; s < 64; s <<= 1) m = fmaxf(m, __shfl_xor(m, s, 64));
  __shared__ float rm[4], rs[4];
  const int wave = t >> 6;
  if ((t & 63) == 0) rm[wave] = m;
  __syncthreads();
  m = fmaxf(fmaxf(rm[0], rm[1]), fmaxf(rm[2], rm[3]));
  float e[9];
  float s = 0.f;
#pragma unroll
  for (int j = 0; j < 9; ++j) {
    e[j] = __expf(v[j] - m);
    s += e[j];
  }
#pragma unroll
  for (int q = 1; q < 64; q <<= 1) s += __shfl_xor(s, q, 64);
  if ((t & 63) == 0) rs[wave] = s;
  __syncthreads();
  const float S = rs[0] + rs[1] + rs[2] + rs[3];
  const float inv = 1.0f / S;
#pragma unroll
  for (int j = 0; j < 9; ++j) out[base + t + j * 256] = f2bf(e[j] * inv);
}

// --------------------------------------------------------------------------
// agg[b][f][d] = sum_n adj_sm[b][f][n] * oeT[b][d][n].
// BM=64(f), BN=128(d), BK=32, K=2304. grid (16, 8). Waves 2x2, tile 32x64.
// --------------------------------------------------------------------------
__global__ __launch_bounds__(256) void k_gemm_agg(const unsigned short* __restrict__ adjsm,
                                                  const unsigned short* __restrict__ oeT,
                                                  float* __restrict__ agg) {
  __shared__ __align__(16) unsigned short As[64 * 32];
  __shared__ __align__(16) unsigned short Bs[128 * 32];
  const int t = threadIdx.x;
  const int lane = t & 63, wave = t >> 6;
  const int r = lane & 15, g = lane >> 4;
  const int wm = wave >> 1, wn = wave & 1;
  const int b = blockIdx.y, bn = blockIdx.x * 128;
  const int ar = t >> 2, aseg = t & 3;
  const int brow = t >> 1, bh = t & 1;
  f32x4 acc[2][4] = {};
  const unsigned short* aptr = adjsm + ((size_t)b * FF + ar) * NOBJ + aseg * 8;
  const unsigned short* bptr = oeT + ((size_t)b * DD + bn + brow) * NOBJ + bh * 16;
  for (int kt = 0; kt < NOBJ / 32; ++kt) {
    const int kb = kt * 32;
    u32x4 av = *(const u32x4*)(aptr + kb);
    u32x4 b0 = ((const u32x4*)(bptr + kb))[0];
    u32x4 b1 = ((const u32x4*)(bptr + kb))[1];
    __syncthreads();
    ((u32x4*)As)[ar * 4 + aseg] = av;
    ((u32x4*)Bs)[brow * 4 + bh * 2 + 0] = b0;
    ((u32x4*)Bs)[brow * 4 + bh * 2 + 1] = b1;
    __syncthreads();
    bf16x8 af[2], bfr[4];
#pragma unroll
    for (int m = 0; m < 2; ++m) af[m] = ((const bf16x8*)As)[(wm * 32 + m * 16 + r) * 4 + g];
#pragma unroll
    for (int n = 0; n < 4; ++n) bfr[n] = ((const bf16x8*)Bs)[(wn * 64 + n * 16 + r) * 4 + g];
#pragma unroll
    for (int m = 0; m < 2; ++m)
#pragma unroll
      for (int n = 0; n < 4; ++n)
        acc[m][n] = __builtin_amdgcn_mfma_f32_16x16x32_bf16(af[m], bfr[n], acc[m][n], 0, 0, 0);
  }
#pragma unroll
  for (int m = 0; m < 2; ++m)
#pragma unroll
    for (int n = 0; n < 4; ++n) {
      const int d = bn + wn * 64 + n * 16 + r;
#pragma unroll
      for (int i = 0; i < 4; ++i) {
        const int f = wm * 32 + m * 16 + g * 4 + i;
        agg[((size_t)b * FF + f) * DD + d] = acc[m][n][i];
      }
    }
}

// --------------------------------------------------------------------------

extern "C" void kernel_launch(void* const* d_in, const int* in_sizes, int n_in,
                              void* d_out, int out_size, void* d_ws, size_t ws_size,
                              hipStream_t stream) {
  (void)in_sizes; (void)n_in; (void)out_size;
  const float* visual = (const float*)d_in[0];
  const float* obj    = (const float*)d_in[1];
  const float* W_v    = (const float*)d_in[2];
  const float* b_v    = (const float*)d_in[3];
  const float* W_o    = (const float*)d_in[4];
  const float* b_o    = (const float*)d_in[5];
  const float* ln_v_g = (const float*)d_in[6];
  const float* ln_v_b = (const float*)d_in[7];
  const float* ln_o_g = (const float*)d_in[8];
  const float* ln_o_b = (const float*)d_in[9];
  const float* ln_ov_g = (const float*)d_in[10];
  const float* ln_ov_b = (const float*)d_in[11];

  // Workspace layout (bytes). Yo is dead after the obj epilogue, so oeT
  // aliases it. Total requirement ~253 MiB.
  char* ws = (char*)d_ws;
  constexpr size_t OFF_WVT = 0;                          // 8 MiB
  constexpr size_t OFF_WOT = 8ull << 20;                 // 8 MiB
  constexpr size_t OFF_YO  = 16ull << 20;                // 144 MiB (fp32 18432x2048)
  constexpr size_t OFF_OET = 16ull << 20;                // alias (72 MiB, after Yo dead)
  constexpr size_t OFF_YV  = 160ull << 20;               // 4 MiB
  constexpr size_t OFF_VEF = 164ull << 20;               // 4 MiB
  constexpr size_t OFF_VEB = 168ull << 20;               // 2 MiB
  constexpr size_t OFF_OEB = 170ull << 20;               // 72 MiB
  constexpr size_t OFF_ADJ = 242ull << 20;               // 4.5 MiB
  constexpr size_t OFF_ADJS = OFF_ADJ + 4718592ull;      // 2.25 MiB
  constexpr size_t OFF_AGG = OFF_ADJS + 2359296ull;      // 4 MiB
  constexpr size_t WS_NEED = OFF_AGG + 4194304ull;
  if (ws_size < WS_NEED) return;  // insufficient scratch -> fail loudly (poisoned out)

  unsigned short* WvT  = (unsigned short*)(ws + OFF_WVT);
  unsigned short* WoT  = (unsigned short*)(ws + OFF_WOT);
  float* Yo            = (float*)(ws + OFF_YO);
  unsigned short* oeT  = (unsigned short*)(ws + OFF_OET);
  float* Yv            = (float*)(ws + OFF_YV);
  float* ve_f          = (float*)(ws + OFF_VEF);
  unsigned short* ve_b = (unsigned short*)(ws + OFF_VEB);
  unsigned short* oe_b = (unsigned short*)(ws + OFF_OEB);
  float* adjT          = (float*)(ws + OFF_ADJ);
  unsigned short* adjs = (unsigned short*)(ws + OFF_ADJS);
  float* agg           = (float*)(ws + OFF_AGG);

  dim3 b256(256);
  // 1) weight transpose+convert
  k_wprep<<<dim3(32, 32), b256, 0, stream>>>(W_v, WvT);
  k_wprep<<<dim3(32, 32), b256, 0, stream>>>(W_o, WoT);
  // 2) branch GEMMs
  k_gemm_xw<<<dim3(16, MV / 128), b256, 0, stream>>>(visual, WvT, b_v, Yv);
  k_gemm_xw<<<dim3(16, MO / 128), b256, 0, stream>>>(obj, WoT, b_o, Yo);
  // 3) tanh + LN epilogues
  k_ep_ln<<<dim3(MV), b256, 0, stream>>>(Yv, nullptr, ln_v_g, ln_v_b, ve_b, ve_f);
  k_ep_ln<<<dim3(MO), b256, 0, stream>>>(Yo, nullptr, ln_o_g, ln_o_b, oe_b, nullptr);
  // 4) oe transpose (oeT aliases Yo; Yo is dead now)
  k_troe<<<dim3(36, 32, 8), b256, 0, stream>>>(oe_b, oeT);
  // 5) adjacency + softmax
  k_gemm_adj<<<dim3(NOBJ / 128, BS), b256, 0, stream>>>(oe_b, ve_b, adjT);
  k_smax<<<dim3(MV), b256, 0, stream>>>(adjT, adjs);
  // 6) aggregation
  k_gemm_agg<<<dim3(DD / 128, BS), b256, 0, stream>>>(adjs, oeT, agg);
  // 7) final add + tanh + LN -> d_out (fp32)
  k_ep_ln<<<dim3(MV), b256, 0, stream>>>(agg, ve_f, ln_ov_g, ln_ov_b, nullptr, (float*)d_out);
}

// Round 2
// 461.554 us; speedup vs baseline: 1.2434x; 1.2434x over previous
//
#include <hip/hip_runtime.h>
#include <cstdint>
#include <cstddef>

// ---------------------------------------------------------------------------
// EnhancedObj: visual/object attention block, bf16-MFMA implementation.
// Shapes (hardcoded): bs=8, F=64, obj=36, d=2048.
//   MO = 18432 object rows, MV = 512 visual rows, NOBJ = 2304.
// Round 2: obj GEMM -> m97 structure (pre-converted bf16 A, global_load_lds
// width-16 staging, 2-barrier loop, bijective XCD swizzle).
// ---------------------------------------------------------------------------

typedef __attribute__((ext_vector_type(4))) float f32x4;
typedef __attribute__((ext_vector_type(4))) unsigned int u32x4;
typedef __attribute__((ext_vector_type(8))) short bf16x8;

#define DD 2048
#define BS 8
#define FF 64
#define NOBJ 2304
#define MO 18432
#define MV 512

__device__ __forceinline__ unsigned short f2bf(float f) {
  unsigned int u = __float_as_uint(f);
  u += 0x7fffu + ((u >> 16) & 1u);          // RTNE (inputs finite)
  return (unsigned short)(u >> 16);
}
__device__ __forceinline__ unsigned int pk2(float a, float b) {
  return (unsigned int)f2bf(a) | ((unsigned int)f2bf(b) << 16);
}

typedef __attribute__((address_space(1))) const unsigned int gas_u32;
typedef __attribute__((address_space(3))) unsigned int las_u32;
__device__ __forceinline__ void gl_lds16(const void* g, void* l) {
  __builtin_amdgcn_global_load_lds((gas_u32*)g, (las_u32*)l, 16, 0, 0);
}

// --------------------------------------------------------------------------
// fp32 -> bf16 bulk convert. Each thread: 16 elements per iter.
// --------------------------------------------------------------------------
__global__ __launch_bounds__(256) void k_cvt_bf16(const float* __restrict__ X,
                                                  unsigned short* __restrict__ O,
                                                  int n16) {
  int idx = blockIdx.x * 256 + threadIdx.x;
  const int stride = gridDim.x * 256;
  for (int i = idx; i < n16; i += stride) {
    const f32x4* src = (const f32x4*)(X + (size_t)i * 16);
    f32x4 a = src[0], b = src[1], c = src[2], d = src[3];
    u32x4 p = {pk2(a.x, a.y), pk2(a.z, a.w), pk2(b.x, b.y), pk2(b.z, b.w)};
    u32x4 q = {pk2(c.x, c.y), pk2(c.z, c.w), pk2(d.x, d.y), pk2(d.z, d.w)};
    u32x4* dst = (u32x4*)(O + (size_t)i * 16);
    dst[0] = p;
    dst[1] = q;
  }
}

// --------------------------------------------------------------------------
// W[k][n] fp32 (2048x2048) -> Wt[n][k] bf16. 64x64 tiles via LDS.
// --------------------------------------------------------------------------
__global__ __launch_bounds__(256) void k_wprep(const float* __restrict__ W,
                                               unsigned short* __restrict__ Wt) {
  __shared__ unsigned short sh[64][65];
  const int t = threadIdx.x;
  const int kb = blockIdx.x * 64, nb = blockIdx.y * 64;
  {
    const int rk = t >> 2, seg = t & 3;
    const float* src = W + (size_t)(kb + rk) * DD + nb + seg * 16;
#pragma unroll
    for (int q = 0; q < 4; ++q) {
      f32x4 x = *(const f32x4*)(src + q * 4);
      sh[rk][seg * 16 + q * 4 + 0] = f2bf(x.x);
      sh[rk][seg * 16 + q * 4 + 1] = f2bf(x.y);
      sh[rk][seg * 16 + q * 4 + 2] = f2bf(x.z);
      sh[rk][seg * 16 + q * 4 + 3] = f2bf(x.w);
    }
  }
  __syncthreads();
  {
    const int nn = t >> 2, ks = t & 3;
    unsigned int o[8];
#pragma unroll
    for (int j = 0; j < 8; ++j)
      o[j] = (unsigned int)sh[ks * 16 + 2 * j][nn] |
             ((unsigned int)sh[ks * 16 + 2 * j + 1][nn] << 16);
    u32x4 p0 = {o[0], o[1], o[2], o[3]};
    u32x4 p1 = {o[4], o[5], o[6], o[7]};
    unsigned short* dst = Wt + (size_t)(nb + nn) * DD + kb + ks * 16;
    ((u32x4*)dst)[0] = p0;
    ((u32x4*)dst)[1] = p1;
  }
}

// --------------------------------------------------------------------------
// Y[M][2048] = A[M][2048](bf16) @ Wt^T + bias.  m97 structure:
// BM=BN=128, BK=32, 256 thr (4 waves 2x2), global_load_lds width-16 staging,
// single LDS buffer, 2 barriers per K-step. Bijective XCD swizzle on tiles.
// grid = (16, M/128); requires (16*M/128) % 8 == 0.
// --------------------------------------------------------------------------
__global__ __launch_bounds__(256) void k_gemm_bb(const unsigned short* __restrict__ A,
                                                 const unsigned short* __restrict__ Bt,
                                                 const float* __restrict__ bias,
                                                 float* __restrict__ Y) {
  __shared__ __align__(16) unsigned short As[128 * 32];
  __shared__ __align__(16) unsigned short Bs[128 * 32];
  const int t = threadIdx.x;
  const int lane = t & 63, wave = t >> 6;
  const int r = lane & 15, g = lane >> 4;
  const int wm = wave >> 1, wn = wave & 1;
  // XCD-aware bijective remap: XCD x owns a contiguous chunk of tile-space.
  const int nwg = gridDim.x * gridDim.y;
  const int orig = blockIdx.y * gridDim.x + blockIdx.x;
  const int per = nwg >> 3;                        // nwg % 8 == 0
  const int lin = (orig & 7) * per + (orig >> 3);
  const int bm = (lin >> 4) * 128;                 // gridDim.x == 16
  const int bn = (lin & 15) * 128;

  // staging: thread t covers row t/4 (+64 on 2nd call), 8 bf16 at col (t&3)*8
  const int srow = t >> 2, scol = (t & 3) * 8;
  const unsigned short* agp = A + (size_t)(bm + srow) * DD + scol;
  const unsigned short* bgp = Bt + (size_t)(bn + srow) * DD + scol;
  unsigned short* alds0 = As + t * 8;
  unsigned short* alds1 = As + 2048 + t * 8;
  unsigned short* blds0 = Bs + t * 8;
  unsigned short* blds1 = Bs + 2048 + t * 8;

  f32x4 acc[4][4] = {};
  for (int kt = 0; kt < DD / 32; ++kt) {
    const int kb = kt * 32;
    gl_lds16(agp + kb, alds0);
    gl_lds16(agp + kb + (size_t)64 * DD, alds1);
    gl_lds16(bgp + kb, blds0);
    gl_lds16(bgp + kb + (size_t)64 * DD, blds1);
    __syncthreads();  // vmcnt(0) drain -> LDS tile ready
    bf16x8 af[4], bfr[4];
#pragma unroll
    for (int m = 0; m < 4; ++m)
      af[m] = *(const bf16x8*)(As + (wm * 64 + m * 16 + r) * 32 + g * 8);
#pragma unroll
    for (int n = 0; n < 4; ++n)
      bfr[n] = *(const bf16x8*)(Bs + (wn * 64 + n * 16 + r) * 32 + g * 8);
#pragma unroll
    for (int m = 0; m < 4; ++m)
#pragma unroll
      for (int n = 0; n < 4; ++n)
        acc[m][n] = __builtin_amdgcn_mfma_f32_16x16x32_bf16(af[m], bfr[n], acc[m][n], 0, 0, 0);
    __syncthreads();  // all waves' frag reads done before next DMA overwrite
  }
#pragma unroll
  for (int m = 0; m < 4; ++m) {
    const int row0 = bm + wm * 64 + m * 16 + g * 4;
#pragma unroll
    for (int n = 0; n < 4; ++n) {
      const int col = bn + wn * 64 + n * 16 + r;
      const float bv = bias[col];
#pragma unroll
      for (int i = 0; i < 4; ++i)
        Y[(size_t)(row0 + i) * DD + col] = acc[m][n][i] + bv;
    }
  }
}

// --------------------------------------------------------------------------
// Y[M][2048] = X[M][2048](fp32) @ W + bias (inline convert). Visual branch.
// --------------------------------------------------------------------------
__global__ __launch_bounds__(256) void k_gemm_xw(const float* __restrict__ X,
                                                 const unsigned short* __restrict__ Wt,
                                                 const float* __restrict__ bias,
                                                 float* __restrict__ Y) {
  __shared__ __align__(16) unsigned short As[128 * 32];
  __shared__ __align__(16) unsigned short Bs[128 * 32];
  const int t = threadIdx.x;
  const int lane = t & 63, wave = t >> 6;
  const int r = lane & 15, g = lane >> 4;
  const int wm = wave >> 1, wn = wave & 1;
  const int bm = blockIdx.y * 128, bn = blockIdx.x * 128;
  const int arow = t >> 1, ah = t & 1;
  f32x4 acc[4][4] = {};
  const float* aptr = X + (size_t)(bm + arow) * DD + ah * 16;
  const unsigned short* bptr = Wt + (size_t)(bn + arow) * DD + ah * 16;
  for (int kt = 0; kt < DD / 32; ++kt) {
    const int kb = kt * 32;
    f32x4 a0 = *(const f32x4*)(aptr + kb);
    f32x4 a1 = *(const f32x4*)(aptr + kb + 4);
    f32x4 a2 = *(const f32x4*)(aptr + kb + 8);
    f32x4 a3 = *(const f32x4*)(aptr + kb + 12);
    u32x4 b0 = *(const u32x4*)(bptr + kb);
    u32x4 b1 = *(const u32x4*)(bptr + kb + 8);
    __syncthreads();
    u32x4 p0 = {pk2(a0.x, a0.y), pk2(a0.z, a0.w), pk2(a1.x, a1.y), pk2(a1.z, a1.w)};
    u32x4 p1 = {pk2(a2.x, a2.y), pk2(a2.z, a2.w), pk2(a3.x, a3.y), pk2(a3.z, a3.w)};
    ((u32x4*)As)[arow * 4 + ah * 2 + 0] = p0;
    ((u32x4*)As)[arow * 4 + ah * 2 + 1] = p1;
    ((u32x4*)Bs)[arow * 4 + ah * 2 + 0] = b0;
    ((u32x4*)Bs)[arow * 4 + ah * 2 + 1] = b1;
    __syncthreads();
    bf16x8 af[4], bfr[4];
#pragma unroll
    for (int m = 0; m < 4; ++m) af[m] = ((const bf16x8*)As)[(wm * 64 + m * 16 + r) * 4 + g];
#pragma unroll
    for (int n = 0; n < 4; ++n) bfr[n] = ((const bf16x8*)Bs)[(wn * 64 + n * 16 + r) * 4 + g];
#pragma unroll
    for (int m = 0; m < 4; ++m)
#pragma unroll
      for (int n = 0; n < 4; ++n)
        acc[m][n] = __builtin_amdgcn_mfma_f32_16x16x32_bf16(af[m], bfr[n], acc[m][n], 0, 0, 0);
  }
#pragma unroll
  for (int m = 0; m < 4; ++m) {
    const int row0 = bm + wm * 64 + m * 16 + g * 4;
#pragma unroll
    for (int n = 0; n < 4; ++n) {
      const int col = bn + wn * 64 + n * 16 + r;
      const float bv = bias[col];
#pragma unroll
      for (int i = 0; i < 4; ++i)
        Y[(size_t)(row0 + i) * DD + col] = acc[m][n][i] + bv;
    }
  }
}

// --------------------------------------------------------------------------
// Row-wise: t = tanh(Y[row] (+ Y2[row])); LN(t)*g+b -> optional bf16 / fp32.
// --------------------------------------------------------------------------
__global__ __launch_bounds__(256) void k_ep_ln(const float* __restrict__ Y,
                                               const float* __restrict__ Y2,
                                               const float* __restrict__ gw,
                                               const float* __restrict__ bw,
                                               unsigned short* __restrict__ obf,
                                               float* __restrict__ of32) {
  const int row = blockIdx.x, t = threadIdx.x;
  const size_t base = (size_t)row * DD + t * 8;
  f32x4 v0 = ((const f32x4*)(Y + base))[0];
  f32x4 v1 = ((const f32x4*)(Y + base))[1];
  if (Y2 != nullptr) {
    v0 += ((const f32x4*)(Y2 + base))[0];
    v1 += ((const f32x4*)(Y2 + base))[1];
  }
  float tv[8];
#pragma unroll
  for (int j = 0; j < 4; ++j) {
    tv[j] = tanhf(v0[j]);
    tv[4 + j] = tanhf(v1[j]);
  }
  float s1 = 0.f, s2 = 0.f;
#pragma unroll
  for (int j = 0; j < 8; ++j) {
    s1 += tv[j];
    s2 += tv[j] * tv[j];
  }
#pragma unroll
  for (int m = 1; m < 64; m <<= 1) {
    s1 += __shfl_xor(s1, m, 64);
    s2 += __shfl_xor(s2, m, 64);
  }
  __shared__ float r1[4], r2[4];
  const int wave = t >> 6;
  if ((t & 63) == 0) {
    r1[wave] = s1;
    r2[wave] = s2;
  }
  __syncthreads();
  const float S1 = r1[0] + r1[1] + r1[2] + r1[3];
  const float S2 = r2[0] + r2[1] + r2[2] + r2[3];
  const float mean = S1 * (1.0f / DD);
  const float var = S2 * (1.0f / DD) - mean * mean;
  const float rstd = rsqrtf(var + 1e-5f);
  f32x4 g0 = ((const f32x4*)(gw + t * 8))[0], g1 = ((const f32x4*)(gw + t * 8))[1];
  f32x4 bb0 = ((const f32x4*)(bw + t * 8))[0], bb1 = ((const f32x4*)(bw + t * 8))[1];
  float o[8];
#pragma unroll
  for (int j = 0; j < 4; ++j) {
    o[j] = (tv[j] - mean) * rstd * g0[j] + bb0[j];
    o[4 + j] = (tv[4 + j] - mean) * rstd * g1[j] + bb1[j];
  }
  if (obf != nullptr) {
    u32x4 p = {pk2(o[0], o[1]), pk2(o[2], o[3]), pk2(o[4], o[5]), pk2(o[6], o[7])};
    *((u32x4*)(obf + base)) = p;
  }
  if (of32 != nullptr) {
    f32x4 w0 = {o[0], o[1], o[2], o[3]}, w1 = {o[4], o[5], o[6], o[7]};
    ((f32x4*)(of32 + base))[0] = w0;
    ((f32x4*)(of32 + base))[1] = w1;
  }
}

// --------------------------------------------------------------------------
// oe[b][n][d] bf16 -> oeT[b][d][n] bf16, 64x64 tiles. grid (36, 32, 8).
// --------------------------------------------------------------------------
__global__ __launch_bounds__(256) void k_troe(const unsigned short* __restrict__ oe,
                                              unsigned short* __restrict__ oeT) {
  __shared__ unsigned short sh[64][65];
  const int t = threadIdx.x;
  const int b = blockIdx.z, nt = blockIdx.x, dt = blockIdx.y;
  {
    const int nn = t >> 2, seg = t & 3;
    const unsigned short* src = oe + ((size_t)b * NOBJ + nt * 64 + nn) * DD + dt * 64 + seg * 16;
    u32x4 x0 = ((const u32x4*)src)[0];
    u32x4 x1 = ((const u32x4*)src)[1];
    const unsigned short* px0 = (const unsigned short*)&x0;
    const unsigned short* px1 = (const unsigned short*)&x1;
#pragma unroll
    for (int j = 0; j < 8; ++j) {
      sh[nn][seg * 16 + j] = px0[j];
      sh[nn][seg * 16 + 8 + j] = px1[j];
    }
  }
  __syncthreads();
  {
    const int dd = t >> 2, ns = t & 3;
    unsigned int o[8];
#pragma unroll
    for (int j = 0; j < 8; ++j)
      o[j] = (unsigned int)sh[ns * 16 + 2 * j][dd] |
             ((unsigned int)sh[ns * 16 + 2 * j + 1][dd] << 16);
    u32x4 p0 = {o[0], o[1], o[2], o[3]};
    u32x4 p1 = {o[4], o[5], o[6], o[7]};
    unsigned short* dst = oeT + ((size_t)b * DD + dt * 64 + dd) * NOBJ + nt * 64 + ns * 16;
    ((u32x4*)dst)[0] = p0;
    ((u32x4*)dst)[1] = p1;
  }
}

// --------------------------------------------------------------------------
// adjT[b][f][n] = (oe[b][n][:] . ve[b][f][:]) / sqrt(2048).
// --------------------------------------------------------------------------
__global__ __launch_bounds__(256) void k_gemm_adj(const unsigned short* __restrict__ oe,
                                                  const unsigned short* __restrict__ veb,
                                                  float* __restrict__ adjT) {
  __shared__ __align__(16) unsigned short As[128 * 32];
  __shared__ __align__(16) unsigned short Bs[64 * 32];
  const int t = threadIdx.x;
  const int lane = t & 63, wave = t >> 6;
  const int r = lane & 15, g = lane >> 4;
  const int wm = wave >> 1, wn = wave & 1;
  const int b = blockIdx.y, bm = blockIdx.x * 128;
  const int arow = t >> 1, ah = t & 1;
  const int br_ = t >> 2, bseg = t & 3;
  f32x4 acc[4][2] = {};
  const unsigned short* aptr = oe + ((size_t)b * NOBJ + bm + arow) * DD + ah * 16;
  const unsigned short* bptr = veb + ((size_t)b * FF + br_) * DD + bseg * 8;
  for (int kt = 0; kt < DD / 32; ++kt) {
    const int kb = kt * 32;
    u32x4 a0 = ((const u32x4*)(aptr + kb))[0];
    u32x4 a1 = ((const u32x4*)(aptr + kb))[1];
    u32x4 bv = *(const u32x4*)(bptr + kb);
    __syncthreads();
    ((u32x4*)As)[arow * 4 + ah * 2 + 0] = a0;
    ((u32x4*)As)[arow * 4 + ah * 2 + 1] = a1;
    ((u32x4*)Bs)[br_ * 4 + bseg] = bv;
    __syncthreads();
    bf16x8 af[4], bfr[2];
#pragma unroll
    for (int m = 0; m < 4; ++m) af[m] = ((const bf16x8*)As)[(wm * 64 + m * 16 + r) * 4 + g];
#pragma unroll
    for (int n = 0; n < 2; ++n) bfr[n] = ((const bf16x8*)Bs)[(wn * 32 + n * 16 + r) * 4 + g];
#pragma unroll
    for (int m = 0; m < 4; ++m)
#pragma unroll
      for (int n = 0; n < 2; ++n)
        acc[m][n] = __builtin_amdgcn_mfma_f32_16x16x32_bf16(af[m], bfr[n], acc[m][n], 0, 0, 0);
  }
  const float scale = 0.02209708691207961f;  // 1/sqrt(2048)
#pragma unroll
  for (int m = 0; m < 4; ++m)
#pragma unroll
    for (int n = 0; n < 2; ++n) {
      const int f = wn * 32 + n * 16 + r;
      const int n0 = bm + wm * 64 + m * 16 + g * 4;
      f32x4 v = acc[m][n];
      v *= scale;
      *(f32x4*)(adjT + ((size_t)b * FF + f) * NOBJ + n0) = v;
    }
}

// --------------------------------------------------------------------------
// Row softmax over 2304 (rows of adjT), write bf16. grid = 512 rows.
// --------------------------------------------------------------------------
__global__ __launch_bounds__(256) void k_smax(const float* __restrict__ adjT,
                                              unsigned short* __restrict__ out) {
  const int t = threadIdx.x;
  const size_t base = (size_t)blockIdx.x * NOBJ;
  float v[9];
#pragma unroll
  for (int j = 0; j < 9; ++j) v[j] = adjT[base + t + j * 256];
  float m = v[0];
#pragma unroll
  for (int j = 1; j < 9; ++j) m = fmaxf(m, v[j]);
#pragma unroll
  for (int s = 1; s < 64; s <<= 1) m = fmaxf(m, __shfl_xor(m, s, 64));
  __shared__ float rm[4], rs[4];
  const int wave = t >> 6;
  if ((t & 63) == 0) rm[wave] = m;
  __syncthreads();
  m = fmaxf(fmaxf(rm[0], rm[1]), fmaxf(rm[2], rm[3]));
  float e[9];
  float s = 0.f;
#pragma unroll
  for (int j = 0; j < 9; ++j) {
    e[j] = __expf(v[j] - m);
    s += e[j];
  }
#pragma unroll
  for (int q = 1; q < 64; q <<= 1) s += __shfl_xor(s, q, 64);
  if ((t & 63) == 0) rs[wave] = s;
  __syncthreads();
  const float S = rs[0] + rs[1] + rs[2] + rs[3];
  const float inv = 1.0f / S;
#pragma unroll
  for (int j = 0; j < 9; ++j) out[base + t + j * 256] = f2bf(e[j] * inv);
}

// --------------------------------------------------------------------------
// agg[b][f][d] = sum_n adj_sm[b][f][n] * oeT[b][d][n].
// --------------------------------------------------------------------------
__global__ __launch_bounds__(256) void k_gemm_agg(const unsigned short* __restrict__ adjsm,
                                                  const unsigned short* __restrict__ oeT,
                                                  float* __restrict__ agg) {
  __shared__ __align__(16) unsigned short As[64 * 32];
  __shared__ __align__(16) unsigned short Bs[128 * 32];
  const int t = threadIdx.x;
  const int lane = t & 63, wave = t >> 6;
  const int r = lane & 15, g = lane >> 4;
  const int wm = wave >> 1, wn = wave & 1;
  const int b = blockIdx.y, bn = blockIdx.x * 128;
  const int ar = t >> 2, aseg = t & 3;
  const int brow = t >> 1, bh = t & 1;
  f32x4 acc[2][4] = {};
  const unsigned short* aptr = adjsm + ((size_t)b * FF + ar) * NOBJ + aseg * 8;
  const unsigned short* bptr = oeT + ((size_t)b * DD + bn + brow) * NOBJ + bh * 16;
  for (int kt = 0; kt < NOBJ / 32; ++kt) {
    const int kb = kt * 32;
    u32x4 av = *(const u32x4*)(aptr + kb);
    u32x4 b0 = ((const u32x4*)(bptr + kb))[0];
    u32x4 b1 = ((const u32x4*)(bptr + kb))[1];
    __syncthreads();
    ((u32x4*)As)[ar * 4 + aseg] = av;
    ((u32x4*)Bs)[brow * 4 + bh * 2 + 0] = b0;
    ((u32x4*)Bs)[brow * 4 + bh * 2 + 1] = b1;
    __syncthreads();
    bf16x8 af[2], bfr[4];
#pragma unroll
    for (int m = 0; m < 2; ++m) af[m] = ((const bf16x8*)As)[(wm * 32 + m * 16 + r) * 4 + g];
#pragma unroll
    for (int n = 0; n < 4; ++n) bfr[n] = ((const bf16x8*)Bs)[(wn * 64 + n * 16 + r) * 4 + g];
#pragma unroll
    for (int m = 0; m < 2; ++m)
#pragma unroll
      for (int n = 0; n < 4; ++n)
        acc[m][n] = __builtin_amdgcn_mfma_f32_16x16x32_bf16(af[m], bfr[n], acc[m][n], 0, 0, 0);
  }
#pragma unroll
  for (int m = 0; m < 2; ++m)
#pragma unroll
    for (int n = 0; n < 4; ++n) {
      const int d = bn + wn * 64 + n * 16 + r;
#pragma unroll
      for (int i = 0; i < 4; ++i) {
        const int f = wm * 32 + m * 16 + g * 4 + i;
        agg[((size_t)b * FF + f) * DD + d] = acc[m][n][i];
      }
    }
}

// --------------------------------------------------------------------------

extern "C" void kernel_launch(void* const* d_in, const int* in_sizes, int n_in,
                              void* d_out, int out_size, void* d_ws, size_t ws_size,
                              hipStream_t stream) {
  (void)in_sizes; (void)n_in; (void)out_size;
  const float* visual = (const float*)d_in[0];
  const float* obj    = (const float*)d_in[1];
  const float* W_v    = (const float*)d_in[2];
  const float* b_v    = (const float*)d_in[3];
  const float* W_o    = (const float*)d_in[4];
  const float* b_o    = (const float*)d_in[5];
  const float* ln_v_g = (const float*)d_in[6];
  const float* ln_v_b = (const float*)d_in[7];
  const float* ln_o_g = (const float*)d_in[8];
  const float* ln_o_b = (const float*)d_in[9];
  const float* ln_ov_g = (const float*)d_in[10];
  const float* ln_ov_b = (const float*)d_in[11];

  // Workspace layout (aliased; ~253 MiB, same footprint as round 1):
  //   [0,8M)     WvT
  //   [8M,16M)   WoT
  //   [16M,88M)  obj_b (bf16)  -> later oe_b (obj_b dead after obj GEMM)
  //   [88M,232M) Yo (fp32)     -> later oeT (Yo dead after obj epilogue)
  //   [232M,..)  Yv, ve_f, ve_b, adjT, adjs, agg
  char* ws = (char*)d_ws;
  constexpr size_t OFF_WVT = 0;
  constexpr size_t OFF_WOT = 8ull << 20;
  constexpr size_t OFF_OBJB = 16ull << 20;   // 72 MiB; aliased by oe_b
  constexpr size_t OFF_YO  = 88ull << 20;    // 144 MiB; aliased by oeT
  constexpr size_t OFF_YV  = 232ull << 20;
  constexpr size_t OFF_VEF = 236ull << 20;
  constexpr size_t OFF_VEB = 240ull << 20;
  constexpr size_t OFF_ADJ = 242ull << 20;
  constexpr size_t OFF_ADJS = OFF_ADJ + 4718592ull;
  constexpr size_t OFF_AGG = OFF_ADJS + 2359296ull;
  constexpr size_t WS_NEED = OFF_AGG + 4194304ull;
  if (ws_size < WS_NEED) return;

  unsigned short* WvT  = (unsigned short*)(ws + OFF_WVT);
  unsigned short* WoT  = (unsigned short*)(ws + OFF_WOT);
  unsigned short* objb = (unsigned short*)(ws + OFF_OBJB);
  unsigned short* oe_b = (unsigned short*)(ws + OFF_OBJB);  // alias (objb dead)
  float* Yo            = (float*)(ws + OFF_YO);
  unsigned short* oeT  = (unsigned short*)(ws + OFF_YO);    // alias (Yo dead)
  float* Yv            = (float*)(ws + OFF_YV);
  float* ve_f          = (float*)(ws + OFF_VEF);
  unsigned short* ve_b = (unsigned short*)(ws + OFF_VEB);
  float* adjT          = (float*)(ws + OFF_ADJ);
  unsigned short* adjs = (unsigned short*)(ws + OFF_ADJS);
  float* agg           = (float*)(ws + OFF_AGG);

  dim3 b256(256);
  // 1) weight transpose+convert, obj fp32->bf16
  k_wprep<<<dim3(32, 32), b256, 0, stream>>>(W_v, WvT);
  k_wprep<<<dim3(32, 32), b256, 0, stream>>>(W_o, WoT);
  k_cvt_bf16<<<dim3(2048), b256, 0, stream>>>(obj, objb, MO * DD / 16);
  // 2) branch GEMMs
  k_gemm_xw<<<dim3(16, MV / 128), b256, 0, stream>>>(visual, WvT, b_v, Yv);
  k_gemm_bb<<<dim3(16, MO / 128), b256, 0, stream>>>(objb, WoT, b_o, Yo);
  // 3) tanh + LN epilogues
  k_ep_ln<<<dim3(MV), b256, 0, stream>>>(Yv, nullptr, ln_v_g, ln_v_b, ve_b, ve_f);
  k_ep_ln<<<dim3(MO), b256, 0, stream>>>(Yo, nullptr, ln_o_g, ln_o_b, oe_b, nullptr);
  // 4) oe transpose (oeT aliases Yo)
  k_troe<<<dim3(36, 32, 8), b256, 0, stream>>>(oe_b, oeT);
  // 5) adjacency + softmax
  k_gemm_adj<<<dim3(NOBJ / 128, BS), b256, 0, stream>>>(oe_b, ve_b, adjT);
  k_smax<<<dim3(MV), b256, 0, stream>>>(adjT, adjs);
  // 6) aggregation
  k_gemm_agg<<<dim3(DD / 128, BS), b256, 0, stream>>>(adjs, oeT, agg);
  // 7) final add + tanh + LN -> d_out (fp32)
  k_ep_ln<<<dim3(MV), b256, 0, stream>>>(agg, ve_f, ln_ov_g, ln_ov_b, nullptr, (float*)d_out);
}